// Round 10
// baseline (1119.178 us; speedup 1.0000x reference)
//
#include <hip/hip_runtime.h>
#include <hip/hip_bf16.h>

#define NA   312      // attributes
#define LAT  64       // latent per attribute (K)
#define HID  128      // hidden per attribute (N)
#define NB   8192     // batch
#define AG   4        // attrs per group = one 1 KB DRAM page per row
#define NAG  (NA / AG)    // 78 groups
#define RB   64       // rows per block (4 waves x 16 rows)
#define NBT  (NB / RB)    // 128 batch tiles

typedef __attribute__((ext_vector_type(8))) short bf16x8;
typedef __attribute__((ext_vector_type(4))) float f32x4;

// fp32 -> bf16 RNE scalar (prep kernel only)
__device__ inline short f2bf(float f) {
    unsigned u = __builtin_bit_cast(unsigned, f);
    u += 0x7FFFu + ((u >> 16) & 1u);
    return (short)(u >> 16);
}

// 8x fp32 -> bf16x8; __float22bfloat162_rn lowers to v_cvt_pk_bf16_f32.
__device__ inline bf16x8 pack8(float4 v0, float4 v1) {
    __hip_bfloat162 c[4] = {
        __float22bfloat162_rn(float2{v0.x, v0.y}),
        __float22bfloat162_rn(float2{v0.z, v0.w}),
        __float22bfloat162_rn(float2{v1.x, v1.y}),
        __float22bfloat162_rn(float2{v1.z, v1.w})};
    bf16x8 f;
    __builtin_memcpy(&f, &c[0], 16);
    return f;
}

// ---------------- prep: W1 [A][LAT][HID] fp32 -> frag-ordered bf16 ----------
// frag entry e = (nt*2+kk)*64 + lane holds 8 bf16:
//   element j = W1[a][ kk*32 + (lane>>4)*8 + j ][ nt*16 + (lane&15) ]
__global__ __launch_bounds__(256, 2) void prep_w1(
    const float* __restrict__ W1, short* __restrict__ w1f)
{
    __shared__ float lds[LAT * HID];   // 32 KB fp32
    const int a   = blockIdx.x;
    const int tid = threadIdx.x;

    const float4* src = reinterpret_cast<const float4*>(W1 + (size_t)a * (LAT * HID));
    float4* ldsv = reinterpret_cast<float4*>(lds);
    #pragma unroll
    for (int i = 0; i < (LAT * HID / 4) / 256; ++i)
        ldsv[i * 256 + tid] = src[i * 256 + tid];
    __syncthreads();

    bf16x8* dst = reinterpret_cast<bf16x8*>(w1f + (size_t)a * (LAT * HID));
    #pragma unroll
    for (int i = 0; i < 4; ++i) {
        const int e    = i * 256 + tid;
        const int nt   = e >> 7;
        const int kk   = (e >> 6) & 1;
        const int lane = e & 63;
        const int n  = nt * 16 + (lane & 15);
        const int k0 = kk * 32 + (lane >> 4) * 8;
        bf16x8 f;
        #pragma unroll
        for (int j = 0; j < 8; ++j)
            f[j] = f2bf(lds[(k0 + j) * HID + n]);
        dst[e] = f;
    }
}

// ---------------- main: page-grouped direct loads, no LDS -------------------
// One block: 4 page-sharing attrs x 64 rows, 4 waves x 16 rows. Each wave
// reads, per row, the full 1 KB page (4 attrs x 256 B) in one 16-instr
// burst (single base + offset immediates) -> full DRAM page utilization.
// Then 4 compute passes (one per attr): B from frag-ordered w1f
// (L2-resident via a-outer grid), fused layer 2 + sigmoid as before.
__global__ __launch_bounds__(256, 2) void attr_decoder_main(
    const float* __restrict__ x,
    const short* __restrict__ w1f,
    const float* __restrict__ b1,
    const float* __restrict__ W2,
    const float* __restrict__ b2,
    float* __restrict__ out)
{
    const int tid  = threadIdx.x;
    const unsigned gi = blockIdx.x;
    const int g    = gi / NBT;          // a-outer: co-resident blocks share g
    const int bt   = gi % NBT;
    const int w    = tid >> 6;
    const int lane = tid & 63;
    const int llo  = lane & 15;
    const int lhi  = lane >> 4;
    const int row  = bt * RB + w * 16 + llo;   // this lane's A-row

    // ---- x loads: 16 dwordx4 off ONE base, offsets < 4 KB (page burst) ----
    const float* xrow = x + (size_t)row * (NA * LAT) + g * (AG * LAT);
    float4 xr[16];
    #pragma unroll
    for (int al = 0; al < AG; ++al) {
        #pragma unroll
        for (int kk = 0; kk < 2; ++kk) {
            const float4* p = reinterpret_cast<const float4*>(
                xrow + al * LAT + kk * 32 + lhi * 8);
            xr[(al * 2 + kk) * 2 + 0] = p[0];
            xr[(al * 2 + kk) * 2 + 1] = p[1];
        }
    }
    bf16x8 af[AG][2];
    #pragma unroll
    for (int al = 0; al < AG; ++al)
        #pragma unroll
        for (int kk = 0; kk < 2; ++kk)
            af[al][kk] = pack8(xr[(al * 2 + kk) * 2], xr[(al * 2 + kk) * 2 + 1]);

    // ---- per-attr: layer-1 MFMA + fused layer-2, reduce, sigmoid, store ----
    #pragma unroll 1
    for (int al = 0; al < AG; ++al) {
        const int a = g * AG + al;
        const bf16x8* wf  = reinterpret_cast<const bf16x8*>(w1f + (size_t)a * (LAT * HID));
        const float*  b1a = b1 + a * HID;
        const float*  w2a = W2 + a * HID;
        float p2[4] = {};
        #pragma unroll
        for (int nt = 0; nt < 8; ++nt) {
            const bf16x8 bf0 = wf[(nt * 2 + 0) * 64 + lane];   // L2-resident
            const bf16x8 bf1 = wf[(nt * 2 + 1) * 64 + lane];
            const int n = nt * 16 + llo;
            const float b1v = b1a[n];
            const float w2v = w2a[n];
            f32x4 acc = {b1v, b1v, b1v, b1v};
            acc = __builtin_amdgcn_mfma_f32_16x16x32_bf16(af[al][0], bf0, acc, 0, 0, 0);
            acc = __builtin_amdgcn_mfma_f32_16x16x32_bf16(af[al][1], bf1, acc, 0, 0, 0);
            #pragma unroll
            for (int r = 0; r < 4; ++r)
                p2[r] = fmaf(fmaxf(acc[r], 0.f), w2v, p2[r]);
        }

        const float ob = b2[a];
        #pragma unroll
        for (int r = 0; r < 4; ++r) {
            float s = p2[r];
            s += __shfl_xor(s, 1);
            s += __shfl_xor(s, 2);
            s += __shfl_xor(s, 4);
            s += __shfl_xor(s, 8);
            s = 1.0f / (1.0f + __expf(-(s + ob)));
            if (llo == 0) {
                const int orow = bt * RB + w * 16 + lhi * 4 + r;
                out[(size_t)orow * NA + a] = s;
            }
        }
    }
}

extern "C" void kernel_launch(void* const* d_in, const int* in_sizes, int n_in,
                              void* d_out, int out_size, void* d_ws, size_t ws_size,
                              hipStream_t stream) {
    const float* x  = (const float*)d_in[0];
    const float* W1 = (const float*)d_in[1];
    const float* b1 = (const float*)d_in[2];
    const float* W2 = (const float*)d_in[3];
    const float* b2 = (const float*)d_in[4];
    float* out = (float*)d_out;
    short* w1f = (short*)d_ws;          // 312*8192 bf16 = 5.1 MB

    hipLaunchKernelGGL(prep_w1, dim3(NA), dim3(256), 0, stream, W1, w1f);
    hipLaunchKernelGGL(attr_decoder_main, dim3(NAG * NBT), dim3(256), 0, stream,
                       x, w1f, b1, W2, b2, out);
}

// Round 11
// 240.239 us; speedup vs baseline: 4.6586x; 4.6586x over previous
//
#include <hip/hip_runtime.h>
#include <hip/hip_bf16.h>

#define NA   312      // attributes
#define LAT  64       // latent per attribute (K)
#define HID  128      // hidden per attribute (N)
#define NB   8192     // batch
#define AG   4        // attrs per group = one 1 KB DRAM page per row
#define NAG  (NA / AG)    // 78 groups
#define RB   64       // rows per block (4 waves x 16 rows)
#define NBT  (NB / RB)    // 128 batch tiles

typedef __attribute__((ext_vector_type(8))) short bf16x8;
typedef __attribute__((ext_vector_type(4))) float f32x4;

// fp32 -> bf16 RNE scalar (prep kernel only)
__device__ inline short f2bf(float f) {
    unsigned u = __builtin_bit_cast(unsigned, f);
    u += 0x7FFFu + ((u >> 16) & 1u);
    return (short)(u >> 16);
}

// 8x fp32 -> bf16x8; __float22bfloat162_rn lowers to v_cvt_pk_bf16_f32.
__device__ inline bf16x8 pack8(float4 v0, float4 v1) {
    __hip_bfloat162 c[4] = {
        __float22bfloat162_rn(float2{v0.x, v0.y}),
        __float22bfloat162_rn(float2{v0.z, v0.w}),
        __float22bfloat162_rn(float2{v1.x, v1.y}),
        __float22bfloat162_rn(float2{v1.z, v1.w})};
    bf16x8 f;
    __builtin_memcpy(&f, &c[0], 16);
    return f;
}

// ---------------- prep: W1 [A][LAT][HID] fp32 -> frag-ordered bf16 ----------
// frag entry e = (nt*2+kk)*64 + lane holds 8 bf16:
//   element j = W1[a][ kk*32 + (lane>>4)*8 + j ][ nt*16 + (lane&15) ]
__global__ __launch_bounds__(256, 2) void prep_w1(
    const float* __restrict__ W1, short* __restrict__ w1f)
{
    __shared__ float lds[LAT * HID];   // 32 KB fp32
    const int a   = blockIdx.x;
    const int tid = threadIdx.x;

    const float4* src = reinterpret_cast<const float4*>(W1 + (size_t)a * (LAT * HID));
    float4* ldsv = reinterpret_cast<float4*>(lds);
    #pragma unroll
    for (int i = 0; i < (LAT * HID / 4) / 256; ++i)
        ldsv[i * 256 + tid] = src[i * 256 + tid];
    __syncthreads();

    bf16x8* dst = reinterpret_cast<bf16x8*>(w1f + (size_t)a * (LAT * HID));
    #pragma unroll
    for (int i = 0; i < 4; ++i) {
        const int e    = i * 256 + tid;
        const int nt   = e >> 7;
        const int kk   = (e >> 6) & 1;
        const int lane = e & 63;
        const int n  = nt * 16 + (lane & 15);
        const int k0 = kk * 32 + (lane >> 4) * 8;
        bf16x8 f;
        #pragma unroll
        for (int j = 0; j < 8; ++j)
            f[j] = f2bf(lds[(k0 + j) * HID + n]);
        dst[e] = f;
    }
}

// ---------------- main: page-grouped direct loads, no LDS -------------------
// One block: 4 page-sharing attrs x 64 rows, 4 waves x 16 rows. Each wave
// reads, per row, the full 1 KB page (4 attrs x 256 B) in one 16-instr
// burst off a single base (offset immediates < 4 KB) -> DRAM page-hit
// scheduling. Per-attr passes are FULLY unrolled (rule #20: all fragment
// indices compile-time constant -> no scratch).
__global__ __launch_bounds__(256, 2) void attr_decoder_main(
    const float* __restrict__ x,
    const short* __restrict__ w1f,
    const float* __restrict__ b1,
    const float* __restrict__ W2,
    const float* __restrict__ b2,
    float* __restrict__ out)
{
    const int tid  = threadIdx.x;
    const unsigned gi = blockIdx.x;
    const int g    = gi / NBT;          // a-outer: co-resident blocks share g
    const int bt   = gi % NBT;
    const int w    = tid >> 6;
    const int lane = tid & 63;
    const int llo  = lane & 15;
    const int lhi  = lane >> 4;
    const int row  = bt * RB + w * 16 + llo;   // this lane's A-row

    // ---- x loads: 16 dwordx4 off ONE base, offsets < 4 KB (page burst) ----
    const float* xrow = x + (size_t)row * (NA * LAT) + g * (AG * LAT);
    float4 xr[16];
    #pragma unroll
    for (int al = 0; al < AG; ++al) {
        #pragma unroll
        for (int kk = 0; kk < 2; ++kk) {
            const float4* p = reinterpret_cast<const float4*>(
                xrow + al * LAT + kk * 32 + lhi * 8);
            xr[(al * 2 + kk) * 2 + 0] = p[0];
            xr[(al * 2 + kk) * 2 + 1] = p[1];
        }
    }
    bf16x8 af[AG][2];
    #pragma unroll
    for (int al = 0; al < AG; ++al)
        #pragma unroll
        for (int kk = 0; kk < 2; ++kk)
            af[al][kk] = pack8(xr[(al * 2 + kk) * 2], xr[(al * 2 + kk) * 2 + 1]);

    // ---- per-attr passes, FULLY unrolled (static af indices) ----
    #pragma unroll
    for (int al = 0; al < AG; ++al) {
        const int a = g * AG + al;
        const bf16x8* wf  = reinterpret_cast<const bf16x8*>(w1f + (size_t)a * (LAT * HID));
        const float*  b1a = b1 + a * HID;
        const float*  w2a = W2 + a * HID;
        float p2[4] = {};
        #pragma unroll
        for (int nt = 0; nt < 8; ++nt) {
            const bf16x8 bf0 = wf[(nt * 2 + 0) * 64 + lane];   // L2-resident
            const bf16x8 bf1 = wf[(nt * 2 + 1) * 64 + lane];
            const int n = nt * 16 + llo;
            const float b1v = b1a[n];
            const float w2v = w2a[n];
            f32x4 acc = {b1v, b1v, b1v, b1v};
            acc = __builtin_amdgcn_mfma_f32_16x16x32_bf16(af[al][0], bf0, acc, 0, 0, 0);
            acc = __builtin_amdgcn_mfma_f32_16x16x32_bf16(af[al][1], bf1, acc, 0, 0, 0);
            #pragma unroll
            for (int r = 0; r < 4; ++r)
                p2[r] = fmaf(fmaxf(acc[r], 0.f), w2v, p2[r]);
        }

        const float ob = b2[a];
        #pragma unroll
        for (int r = 0; r < 4; ++r) {
            float s = p2[r];
            s += __shfl_xor(s, 1);
            s += __shfl_xor(s, 2);
            s += __shfl_xor(s, 4);
            s += __shfl_xor(s, 8);
            s = 1.0f / (1.0f + __expf(-(s + ob)));
            if (llo == 0) {
                const int orow = bt * RB + w * 16 + lhi * 4 + r;
                out[(size_t)orow * NA + a] = s;
            }
        }
    }
}

extern "C" void kernel_launch(void* const* d_in, const int* in_sizes, int n_in,
                              void* d_out, int out_size, void* d_ws, size_t ws_size,
                              hipStream_t stream) {
    const float* x  = (const float*)d_in[0];
    const float* W1 = (const float*)d_in[1];
    const float* b1 = (const float*)d_in[2];
    const float* W2 = (const float*)d_in[3];
    const float* b2 = (const float*)d_in[4];
    float* out = (float*)d_out;
    short* w1f = (short*)d_ws;          // 312*8192 bf16 = 5.1 MB

    hipLaunchKernelGGL(prep_w1, dim3(NA), dim3(256), 0, stream, W1, w1f);
    hipLaunchKernelGGL(attr_decoder_main, dim3(NAG * NBT), dim3(256), 0, stream,
                       x, w1f, b1, W2, b2, out);
}